// Round 2
// baseline (120.458 us; speedup 1.0000x reference)
//
#include <hip/hip_runtime.h>
#include <hip/hip_bf16.h>
#include <hip/hip_fp16.h>

// Problem: B=8192, T=128, D=7, I=128, C=10, H=64, L=128
// R16: ONE plain kernel, 512 fully-independent blocks (bg 0..31, tg 0..15).
// Key insight: the sPack tile main block (bg,tg) consumes is produced entirely
// by zs block (mb=tg, ns=bg) -> fuse per-block, sPack stays in LDS.
// attn (full 128-col softmax, keep 8 cols) + leaf softmax recomputed per
// block (16x redundant, trivial FLOPs). No workspace, no grid sync, no
// cooperative launch (R15 failed: coop launch didn't execute under harness).
// Epilogue: hipMemsetAsync(out) + 16-way atomicAdd.
//
// LDS layout (63488 B, static, 2 blocks/CU):
//  A 0     : zs  half [8 tree][256 b][8]  = 32768  (d0..6 = s, d7 junk)
//  B 32768 : phase2 hids bf16 4wv*4608=18432 | phase3/4 lpB uint4[8][8][20]
//            =20480 | epilogue red f32[2560]=10240   (sequential overlay)
//  C 53248 : lps half [256][12] = 6144   (leaf probs staging)
//  D 59392 : attnV half [256][8] = 4096

#define BB 8192
#define TT 128
#define II 128
#define CC 10
#define HH 64

typedef __attribute__((ext_vector_type(8))) short short8;
typedef __attribute__((ext_vector_type(16))) float floatx16;

static __device__ inline unsigned int pkbf(float lo, float hi) {
  __hip_bfloat162 h = __float22bfloat162_rn(make_float2(lo, hi));
  unsigned int u;
  __builtin_memcpy(&u, &h, 4);
  return u;
}

static __device__ inline unsigned int pkh(float lo, float hi) {
  __half2 h = __float22half2_rn(make_float2(lo, hi));
  unsigned int u;
  __builtin_memcpy(&u, &h, 4);
  return u;
}

static __device__ inline short8 cvt8(float4 a, float4 b) {
  union { short8 v; unsigned int u[4]; } r;
  r.u[0] = pkbf(a.x, a.y);
  r.u[1] = pkbf(a.z, a.w);
  r.u[2] = pkbf(b.x, b.y);
  r.u[3] = pkbf(b.z, b.w);
  return r.v;
}

__global__ __launch_bounds__(256, 2) void fused_kernel(
    const float* __restrict__ x, const float* __restrict__ mask,
    const float* __restrict__ thr, const float* __restrict__ lo,
    const float* __restrict__ W1, const float* __restrict__ b1,
    const float* __restrict__ W2, const float* __restrict__ b2,
    float* __restrict__ out) {
  __shared__ __align__(16) char smem_raw[63488];
  const int tid = threadIdx.x;
  const int wv = tid >> 6, lane = tid & 63;
  const int half = lane >> 5, l31 = lane & 31;
  const int tg = blockIdx.x >> 5;   // 0..15: trees tg*8..tg*8+7
  const int bg = blockIdx.x & 31;   // 0..31: rows bg*256..bg*256+255

  __half* zsl = (__half*)smem_raw;                       // region A

  // ==================== Phase 1: zs -> LDS (region A) =======================
  // Verified zs branch with mb=tg, ns=bg; global dump removed.
  {
    const int m0 = tg * 56;
    short8 af0[8], af1[8];
    {
      const float* mrow0 = mask + (size_t)(m0 + l31) * II + half * 8;
      int mr1 = m0 + 28 + l31; if (mr1 > 895) mr1 = 895;
      const float* mrow1 = mask + (size_t)mr1 * II + half * 8;
#pragma unroll
      for (int s = 0; s < 8; ++s) {
        af0[s] = cvt8(*(const float4*)(mrow0 + s * 16),
                      *(const float4*)(mrow0 + s * 16 + 4));
        af1[s] = cvt8(*(const float4*)(mrow1 + s * 16),
                      *(const float4*)(mrow1 + s * 16 + 4));
      }
    }
    float th0[16], th1[16];
#pragma unroll
    for (int r = 0; r < 16; ++r) {
      int rw = (r & 3) + 8 * (r >> 2) + 4 * half;
      th0[r] = thr[m0 + rw];
      int m1 = m0 + 28 + rw;
      th1[r] = thr[m1 > 895 ? 895 : m1];
    }

#pragma unroll
    for (int nb = 0; nb < 2; ++nb) {
      const int nl = wv * 64 + nb * 32;
      const float* xrow = x + (size_t)(bg * 256 + nl + l31) * II + half * 8;
      short8 xf[8];
#pragma unroll
      for (int s = 0; s < 8; ++s)
        xf[s] = cvt8(*(const float4*)(xrow + s * 16),
                     *(const float4*)(xrow + s * 16 + 4));
      floatx16 acc0, acc1;
#pragma unroll
      for (int i = 0; i < 16; ++i) { acc0[i] = 0.f; acc1[i] = 0.f; }
#pragma unroll
      for (int s = 0; s < 8; ++s) {
        acc0 = __builtin_amdgcn_mfma_f32_32x32x16_bf16(af0[s], xf[s], acc0, 0, 0, 0);
        acc1 = __builtin_amdgcn_mfma_f32_32x32x16_bf16(af1[s], xf[s], acc1, 0, 0, 0);
      }
#pragma unroll
      for (int r = 0; r < 16; ++r) {
        int row = (r & 3) + 8 * (r >> 2) + 4 * half;   // 0..31
        if (row < 28) {
          int tl = row / 7;
          int d = row - tl * 7;
          float z = acc0[r] - th0[r];
          float o = 0.5f * (z / (1.f + fabsf(z)) + 1.f);
          zsl[(tl * 256 + nl + l31) * 8 + d] = __float2half(o);
          z = acc1[r] - th1[r];
          o = 0.5f * (z / (1.f + fabsf(z)) + 1.f);
          zsl[((tl + 4) * 256 + nl + l31) * 8 + d] = __float2half(o);
        }
      }
    }
  }

  // ============ Phase 2: attn (2 passes of 128 rows), keep 8 cols ===========
  {
    const int tsel = tg >> 2, lsel = tg & 3;
    __half* attnV = (__half*)(smem_raw + 59392);         // region D
    for (int p = 0; p < 2; ++p) {
      const int b0 = bg * 256 + p * 128 + wv * 32;

      short8 axf[8];
      const float* xrow = x + (size_t)(b0 + l31) * II + half * 8;
#pragma unroll
      for (int s = 0; s < 8; ++s)
        axf[s] = cvt8(*(const float4*)(xrow + s * 16),
                      *(const float4*)(xrow + s * 16 + 4));

      floatx16 acch[2];
#pragma unroll
      for (int i = 0; i < 16; ++i) { acch[0][i] = 0.f; acch[1][i] = 0.f; }
#pragma unroll
      for (int s = 0; s < 8; ++s) {
#pragma unroll
        for (int tile = 0; tile < 2; ++tile) {
          union { short8 v; unsigned int u[4]; } wf;
#pragma unroll
          for (int jp = 0; jp < 4; ++jp) {
            int k0 = s * 16 + half * 8 + jp * 2;
            float f0 = W1[(size_t)k0 * HH + tile * 32 + l31];
            float f1 = W1[(size_t)(k0 + 1) * HH + tile * 32 + l31];
            wf.u[jp] = pkbf(f0, f1);
          }
          acch[tile] = __builtin_amdgcn_mfma_f32_32x32x16_bf16(
              axf[s], wf.v, acch[tile], 0, 0, 0);
        }
      }
      __hip_bfloat16* hids = (__hip_bfloat16*)(smem_raw + 32768) + wv * (32 * 72);
#pragma unroll
      for (int tile = 0; tile < 2; ++tile) {
        float bh = b1[tile * 32 + l31];
#pragma unroll
        for (int r = 0; r < 16; ++r) {
          int row = (r & 3) + 8 * (r >> 2) + 4 * half;
          hids[row * 72 + tile * 32 + l31] =
              __float2bfloat16(fmaxf(acch[tile][r] + bh, 0.f));
        }
      }
      __syncthreads();

      short8 ahf[4];
#pragma unroll
      for (int s = 0; s < 4; ++s)
        ahf[s] = *(const short8*)(hids + l31 * 72 + s * 16 + half * 8);

      floatx16 accl[4];
#pragma unroll
      for (int tile = 0; tile < 4; ++tile) {
#pragma unroll
        for (int i = 0; i < 16; ++i) accl[tile][i] = 0.f;
#pragma unroll
        for (int s = 0; s < 4; ++s) {
          union { short8 v; unsigned int u[4]; } wf;
#pragma unroll
          for (int jp = 0; jp < 4; ++jp) {
            int k0 = s * 16 + half * 8 + jp * 2;
            float f0 = W2[(size_t)k0 * TT + tile * 32 + l31];
            float f1 = W2[(size_t)(k0 + 1) * TT + tile * 32 + l31];
            wf.u[jp] = pkbf(f0, f1);
          }
          accl[tile] = __builtin_amdgcn_mfma_f32_32x32x16_bf16(
              ahf[s], wf.v, accl[tile], 0, 0, 0);
        }
        float bt = b2[tile * 32 + l31];
#pragma unroll
        for (int i = 0; i < 16; ++i) accl[tile][i] += bt;
      }

      float mrow[16];
#pragma unroll
      for (int r = 0; r < 16; ++r)
        mrow[r] = fmaxf(fmaxf(accl[0][r], accl[1][r]),
                        fmaxf(accl[2][r], accl[3][r]));
#pragma unroll
      for (int msk = 1; msk <= 16; msk <<= 1)
#pragma unroll
        for (int r = 0; r < 16; ++r)
          mrow[r] = fmaxf(mrow[r], __shfl_xor(mrow[r], msk, 64));
      float srow[16];
#pragma unroll
      for (int r = 0; r < 16; ++r) srow[r] = 0.f;
#pragma unroll
      for (int tile = 0; tile < 4; ++tile)
#pragma unroll
        for (int r = 0; r < 16; ++r) {
          float e = __expf(accl[tile][r] - mrow[r]);
          accl[tile][r] = e;
          srow[r] += e;
        }
#pragma unroll
      for (int msk = 1; msk <= 16; msk <<= 1)
#pragma unroll
        for (int r = 0; r < 16; ++r)
          srow[r] += __shfl_xor(srow[r], msk, 64);
#pragma unroll
      for (int r = 0; r < 16; ++r) srow[r] = 1.f / srow[r];

      // keep only cols tg*8..tg*8+7 -> attnV[local row][0..7]
#pragma unroll
      for (int tile = 0; tile < 4; ++tile) {
        if (tile == tsel) {
#pragma unroll
          for (int r = 0; r < 16; ++r) {
            int row = (r & 3) + 8 * (r >> 2) + 4 * half;
            if ((l31 >> 3) == lsel)
              attnV[(p * 128 + wv * 32 + row) * 8 + (l31 & 7)] =
                  __float2half(accl[tile][r] * srow[r]);
          }
        }
      }
      __syncthreads();
    }
  }

  // ======= Phase 3: leaf softmax -> compact fp16 B-frags in LDS (B) =========
  {
    __half* lps = (__half*)(smem_raw + 53248);           // region C
    uint4* lpB = (uint4*)(smem_raw + 32768);             // region B
    for (int tt = 0; tt < 4; ++tt) {
      {
        int tl = tid >> 7, l = tid & 127;
        const float* row = lo + ((size_t)(tg * 8 + tt * 2 + tl) * 128 + l) * CC;
        float v[CC];
        float m = -1e30f;
#pragma unroll
        for (int c = 0; c < CC; ++c) { v[c] = row[c]; m = fmaxf(m, v[c]); }
        float s = 0.f;
#pragma unroll
        for (int c = 0; c < CC; ++c) { v[c] = __expf(v[c] - m); s += v[c]; }
        float inv = 1.f / s;
        __half* o = lps + (tl * 128 + l) * 12;
#pragma unroll
        for (int c = 0; c < CC; ++c) o[c] = __float2half(v[c] * inv);
      }
      __syncthreads();
#pragma unroll
      for (int jj = 0; jj < 4; ++jj) {
        int idx = tid + 256 * jj;          // 0..1023
        int tl = idx >> 9, rem = idx & 511;
        int s = rem >> 6, ln = rem & 63;
        int hf = ln >> 5, n = ln & 31;
        if (n < CC) {
          unsigned int wd[4];
#pragma unroll
          for (int jp = 0; jp < 4; ++jp) {
            int l0 = s * 16 + hf * 8 + jp * 2;
            float f0 = __half2float(lps[(tl * 128 + l0) * 12 + n]);
            float f1 = __half2float(lps[(tl * 128 + l0 + 1) * 12 + n]);
            wd[jp] = pkh(f0, f1);
          }
          lpB[((tt * 2 + tl) * 8 + s) * 20 + n * 2 + hf] =
              make_uint4(wd[0], wd[1], wd[2], wd[3]);
        }
      }
      __syncthreads();
    }
  }

  // ==================== Phase 4: main contraction ===========================
  {
    const uint4* zsl4 = (const uint4*)smem_raw;
    const uint4* lpB = (const uint4*)(smem_raw + 32768);
    const uint4* aV = (const uint4*)(smem_raw + 59392);
    const int bl = wv * 64 + l31;          // local row of acc0; acc1 = bl+32

    __half av0[8], av1[8];
    *(uint4*)av0 = aV[bl];
    *(uint4*)av1 = aV[bl + 32];

    floatx16 acc0, acc1;
#pragma unroll
    for (int i = 0; i < 16; ++i) { acc0[i] = 0.f; acc1[i] = 0.f; }

#pragma unroll
    for (int it = 0; it < 8; ++it) {
      uint4 sv0 = zsl4[it * 256 + bl];
      uint4 sv1 = zsl4[it * 256 + bl + 32];
      uint4 bf[8];
#pragma unroll
      for (int s = 0; s < 8; ++s)
        bf[s] = (l31 < CC) ? lpB[(it * 8 + s) * 20 + l31 * 2 + half]
                           : make_uint4(0u, 0u, 0u, 0u);

      __half2 pl2q[2][4];
      float wvq[2][8];
#pragma unroll
      for (int q = 0; q < 2; ++q) {
        const __half* sh = (const __half*)(q ? &sv1 : &sv0);
        float s0 = __half2float(sh[0]), s1 = __half2float(sh[1]);
        float s2 = __half2float(sh[2]), s3 = __half2float(sh[3]);
        float s4 = __half2float(sh[4]), s5 = __half2float(sh[5]);
        float s6 = __half2float(sh[6]);
        float A  = __half2float(q ? av1[it] : av0[it]);

        float s0c = 1.f - s0, s1c = 1.f - s1, s2c = 1.f - s2;
        float t0 = s0 * s1, t1 = s0c * s1, t2 = s0 * s1c, t3 = s0c * s1c;
        float pl[8];
        pl[0] = t0 * s2;  pl[1] = t1 * s2;  pl[2] = t2 * s2;  pl[3] = t3 * s2;
        pl[4] = t0 * s2c; pl[5] = t1 * s2c; pl[6] = t2 * s2c; pl[7] = t3 * s2c;
        float sel3 = half ? (1.f - s3) : s3;
        float Af = A * sel3;
        float s4c = 1.f - s4, s5c = 1.f - s5;
        float as6 = Af * s6, as6c = Af * (1.f - s6);
        float u0 = s4 * s5, u1 = s4c * s5, u2 = s4 * s5c, u3 = s4c * s5c;
        wvq[q][0] = u0 * as6;  wvq[q][1] = u1 * as6;
        wvq[q][2] = u2 * as6;  wvq[q][3] = u3 * as6;
        wvq[q][4] = u0 * as6c; wvq[q][5] = u1 * as6c;
        wvq[q][6] = u2 * as6c; wvq[q][7] = u3 * as6c;
#pragma unroll
        for (int jp = 0; jp < 4; ++jp)
          pl2q[q][jp] = __float22half2_rn(make_float2(pl[jp * 2], pl[jp * 2 + 1]));
      }

#pragma unroll
      for (int s = 0; s < 8; ++s) {
        union { short8 v; __half2 h[4]; } a0, a1;
        __half2 w20 = __half2half2(__float2half(wvq[0][s]));
        __half2 w21 = __half2half2(__float2half(wvq[1][s]));
#pragma unroll
        for (int jp = 0; jp < 4; ++jp) {
          a0.h[jp] = __hmul2(pl2q[0][jp], w20);
          a1.h[jp] = __hmul2(pl2q[1][jp], w21);
        }
        acc0 = __builtin_amdgcn_mfma_f32_32x32x16_f16(
            a0.v, *(const short8*)&bf[s], acc0, 0, 0, 0);
        acc1 = __builtin_amdgcn_mfma_f32_32x32x16_f16(
            a1.v, *(const short8*)&bf[s], acc1, 0, 0, 0);
      }
    }

    // ---------------- epilogue: LDS transpose -> atomicAdd ------------------
    __syncthreads();   // all lpB/zsl reads done before red overwrites B
    float* red = (float*)(smem_raw + 32768);
    if (l31 < CC) {
#pragma unroll
      for (int r = 0; r < 16; ++r) {
        int row = (r & 3) + 8 * (r >> 2) + 4 * half;
        red[(wv * 64 + row) * 10 + l31] = acc0[r];
        red[(wv * 64 + 32 + row) * 10 + l31] = acc1[r];
      }
    }
    __syncthreads();
#pragma unroll
    for (int j = 0; j < 10; ++j) {
      int idx = tid + 256 * j;   // 0..2559
      atomicAdd(out + (size_t)bg * 2560 + idx, red[idx]);
    }
  }
}

// ---------------------------------------------------------------------------
extern "C" void kernel_launch(void* const* d_in, const int* in_sizes, int n_in,
                              void* d_out, int out_size, void* d_ws, size_t ws_size,
                              hipStream_t stream) {
  const float* x    = (const float*)d_in[0];
  const float* mask = (const float*)d_in[1];
  const float* thr  = (const float*)d_in[2];
  const float* lo   = (const float*)d_in[3];
  const float* W1   = (const float*)d_in[4];
  const float* b1   = (const float*)d_in[5];
  const float* W2   = (const float*)d_in[6];
  const float* b2   = (const float*)d_in[7];
  float* out = (float*)d_out;

  hipMemsetAsync(out, 0, (size_t)out_size * sizeof(float), stream);
  fused_kernel<<<512, 256, 0, stream>>>(x, mask, thr, lo, W1, b1, W2, b2, out);
}

// Round 3
// 117.444 us; speedup vs baseline: 1.0257x; 1.0257x over previous
//
#include <hip/hip_runtime.h>
#include <hip/hip_bf16.h>
#include <hip/hip_fp16.h>

// Problem: B=8192, T=128, D=7, I=128, C=10, H=64, L=128
// R17: two plain kernels (R16's coop/1-kernel lesson: no grid sync available;
// R16 counters: 59us, VALU 38%, Mfma 9.6%, occ 17.8% -> latency-bound with
// 16x-redundant attn/prep). Split:
//  A: prep_kernel (128 blocks): attn -> attnB [8192][128] fp16 (64 blocks,
//     verified R0 branch) + leaf softmax -> COMPACT LPb [t][s][n<10][hf]
//     uint4 = 320 KB (64 blocks).
//  B: main_kernel (1024 blocks, 128 rows each): zs in LDS (never leaves) +
//     main contraction. LDS 38 KB, launch_bounds(256,4) -> 4 blocks/CU =
//     16 waves/CU (2x R16). Epilogue atomicAdd (out pre-zeroed by memset).
// ws: attnB fp16 at float-slot 0 (524288), LPb at 524288 (81920 floats).

#define BB 8192
#define TT 128
#define II 128
#define CC 10
#define HH 64

#define OFF_LPB 524288

typedef __attribute__((ext_vector_type(8))) short short8;
typedef __attribute__((ext_vector_type(16))) float floatx16;

static __device__ inline unsigned int pkbf(float lo, float hi) {
  __hip_bfloat162 h = __float22bfloat162_rn(make_float2(lo, hi));
  unsigned int u;
  __builtin_memcpy(&u, &h, 4);
  return u;
}

static __device__ inline unsigned int pkh(float lo, float hi) {
  __half2 h = __float22half2_rn(make_float2(lo, hi));
  unsigned int u;
  __builtin_memcpy(&u, &h, 4);
  return u;
}

static __device__ inline short8 cvt8(float4 a, float4 b) {
  union { short8 v; unsigned int u[4]; } r;
  r.u[0] = pkbf(a.x, a.y);
  r.u[1] = pkbf(a.z, a.w);
  r.u[2] = pkbf(b.x, b.y);
  r.u[3] = pkbf(b.z, b.w);
  return r.v;
}

// ---------------- Kernel A: attn (blocks 0..63) + prep (64..127) ------------
__global__ __launch_bounds__(256, 2) void prep_kernel(
    const float* __restrict__ x, const float* __restrict__ lo,
    const float* __restrict__ W1, const float* __restrict__ b1,
    const float* __restrict__ W2, const float* __restrict__ b2,
    __half* __restrict__ attnB, unsigned int* __restrict__ lpbG) {
  __shared__ __align__(16) char smem_raw[18432];
  const int blk = blockIdx.x;
  const int tid = threadIdx.x;
  const int wv = tid >> 6, lane = tid & 63;
  const int half = lane >> 5, l31 = lane & 31;

  if (blk < 64) {
    // ---------------- attn: 128 b-rows/block, 32/wave (R0-verified) ---------
    const int b0 = blk * 128 + wv * 32;

    short8 axf[8];
    const float* xrow = x + (size_t)(b0 + l31) * II + half * 8;
#pragma unroll
    for (int s = 0; s < 8; ++s)
      axf[s] = cvt8(*(const float4*)(xrow + s * 16),
                    *(const float4*)(xrow + s * 16 + 4));

    floatx16 acch[2];
#pragma unroll
    for (int i = 0; i < 16; ++i) { acch[0][i] = 0.f; acch[1][i] = 0.f; }
#pragma unroll
    for (int s = 0; s < 8; ++s) {
#pragma unroll
      for (int tile = 0; tile < 2; ++tile) {
        union { short8 v; unsigned int u[4]; } wf;
#pragma unroll
        for (int jp = 0; jp < 4; ++jp) {
          int k0 = s * 16 + half * 8 + jp * 2;
          float f0 = W1[(size_t)k0 * HH + tile * 32 + l31];
          float f1 = W1[(size_t)(k0 + 1) * HH + tile * 32 + l31];
          wf.u[jp] = pkbf(f0, f1);
        }
        acch[tile] = __builtin_amdgcn_mfma_f32_32x32x16_bf16(
            axf[s], wf.v, acch[tile], 0, 0, 0);
      }
    }
    __hip_bfloat16* hids = (__hip_bfloat16*)smem_raw + wv * (32 * 72);
#pragma unroll
    for (int tile = 0; tile < 2; ++tile) {
      float bh = b1[tile * 32 + l31];
#pragma unroll
      for (int r = 0; r < 16; ++r) {
        int row = (r & 3) + 8 * (r >> 2) + 4 * half;
        hids[row * 72 + tile * 32 + l31] =
            __float2bfloat16(fmaxf(acch[tile][r] + bh, 0.f));
      }
    }
    __syncthreads();

    short8 ahf[4];
#pragma unroll
    for (int s = 0; s < 4; ++s)
      ahf[s] = *(const short8*)(hids + l31 * 72 + s * 16 + half * 8);

    floatx16 accl[4];
#pragma unroll
    for (int tile = 0; tile < 4; ++tile) {
#pragma unroll
      for (int i = 0; i < 16; ++i) accl[tile][i] = 0.f;
#pragma unroll
      for (int s = 0; s < 4; ++s) {
        union { short8 v; unsigned int u[4]; } wf;
#pragma unroll
        for (int jp = 0; jp < 4; ++jp) {
          int k0 = s * 16 + half * 8 + jp * 2;
          float f0 = W2[(size_t)k0 * TT + tile * 32 + l31];
          float f1 = W2[(size_t)(k0 + 1) * TT + tile * 32 + l31];
          wf.u[jp] = pkbf(f0, f1);
        }
        accl[tile] = __builtin_amdgcn_mfma_f32_32x32x16_bf16(
            ahf[s], wf.v, accl[tile], 0, 0, 0);
      }
      float bt = b2[tile * 32 + l31];
#pragma unroll
      for (int i = 0; i < 16; ++i) accl[tile][i] += bt;
    }

    float mrow[16];
#pragma unroll
    for (int r = 0; r < 16; ++r)
      mrow[r] = fmaxf(fmaxf(accl[0][r], accl[1][r]),
                      fmaxf(accl[2][r], accl[3][r]));
#pragma unroll
    for (int msk = 1; msk <= 16; msk <<= 1)
#pragma unroll
      for (int r = 0; r < 16; ++r)
        mrow[r] = fmaxf(mrow[r], __shfl_xor(mrow[r], msk, 64));
    float srow[16];
#pragma unroll
    for (int r = 0; r < 16; ++r) srow[r] = 0.f;
#pragma unroll
    for (int tile = 0; tile < 4; ++tile)
#pragma unroll
      for (int r = 0; r < 16; ++r) {
        float e = __expf(accl[tile][r] - mrow[r]);
        accl[tile][r] = e;
        srow[r] += e;
      }
#pragma unroll
    for (int msk = 1; msk <= 16; msk <<= 1)
#pragma unroll
      for (int r = 0; r < 16; ++r)
        srow[r] += __shfl_xor(srow[r], msk, 64);
#pragma unroll
    for (int r = 0; r < 16; ++r) srow[r] = 1.f / srow[r];

#pragma unroll
    for (int tile = 0; tile < 4; ++tile)
#pragma unroll
      for (int r = 0; r < 16; ++r) {
        int row = (r & 3) + 8 * (r >> 2) + 4 * half;
        attnB[(size_t)(b0 + row) * TT + tile * 32 + l31] =
            __float2half(accl[tile][r] * srow[r]);
      }

  } else {
    // ------- prep: leaf softmax -> COMPACT fp16 B-frags (global) -----------
    float* lps = (float*)smem_raw;   // [2][128][12] f32 = 12288 B
    const int t0 = (blk - 64) * 2;
    {
      int tl = tid >> 7, l = tid & 127;
      const float* row = lo + ((size_t)(t0 + tl) * 128 + l) * CC;
      float v[CC];
      float m = -1e30f;
#pragma unroll
      for (int c = 0; c < CC; ++c) { v[c] = row[c]; m = fmaxf(m, v[c]); }
      float s = 0.f;
#pragma unroll
      for (int c = 0; c < CC; ++c) { v[c] = __expf(v[c] - m); s += v[c]; }
      float inv = 1.f / s;
      float* o = lps + (tl * 128 + l) * 12;
#pragma unroll
      for (int c = 0; c < CC; ++c) o[c] = v[c] * inv;
    }
    __syncthreads();

    // compact layout: [tree][s][n][hf] uint4, idx = tree*160 + s*20 + n*2 + hf
#pragma unroll
    for (int jj = 0; jj < 2; ++jj) {
      int idx = jj * 256 + tid;          // 0..319
      if (idx < 320) {
        int tl = idx / 160, rem = idx - tl * 160;
        int s = rem / 20, e = rem - s * 20;
        int n = e >> 1, hf = e & 1;
        unsigned int wd[4];
#pragma unroll
        for (int jp = 0; jp < 4; ++jp) {
          int l0 = s * 16 + hf * 8 + jp * 2;
          float f0 = lps[(tl * 128 + l0) * 12 + n];
          float f1 = lps[(tl * 128 + l0 + 1) * 12 + n];
          wd[jp] = pkh(f0, f1);
        }
        ((uint4*)lpbG)[(size_t)(t0 + tl) * 160 + s * 20 + n * 2 + hf] =
            make_uint4(wd[0], wd[1], wd[2], wd[3]);
      }
    }
  }
}

// ---------------- Kernel B: zs (LDS-resident) + main contraction ------------
// 1024 blocks: bg2 = blk>>4 (128 rows), tg = blk&15 (8 trees).
// LDS: zsl half[8][128][8]=16384 | attnV4 2048 | lpB4 20480  (38912 B)
// -> 4 blocks/CU at VGPR<=128 (launch_bounds(256,4)).
__global__ __launch_bounds__(256, 4) void main_kernel(
    const float* __restrict__ x, const float* __restrict__ mask,
    const float* __restrict__ thr, const __half* __restrict__ attnB,
    const unsigned int* __restrict__ lpbG, float* __restrict__ out) {
  __shared__ __align__(16) char smem_raw[38912];
  const int tid = threadIdx.x;
  const int wv = tid >> 6, lane = tid & 63;
  const int half = lane >> 5, l31 = lane & 31;
  const int bg2 = blockIdx.x >> 4;   // 0..63: rows bg2*128..+128
  const int tg = blockIdx.x & 15;    // 0..15: trees tg*8..+8

  __half* zsl = (__half*)smem_raw;                   // [8][128][8]
  uint4* attnV4 = (uint4*)(smem_raw + 16384);        // [128]
  uint4* lpB4 = (uint4*)(smem_raw + 18432);          // [1280]

  // ---- stage attnV (2 KB) + compact lpB (20 KB); latency hides under zs ----
  if (tid < 128)
    attnV4[tid] = ((const uint4*)attnB)[(size_t)(bg2 * 128 + tid) * 16 + tg];
  {
    const uint4* lg = (const uint4*)lpbG + (size_t)tg * 1280;
#pragma unroll
    for (int j = 0; j < 5; ++j) lpB4[j * 256 + tid] = lg[j * 256 + tid];
  }

  // ==================== Phase 1: zs -> LDS ==================================
  {
    const int m0 = tg * 56;
    short8 xf[8];
    const float* xrow = x + (size_t)(bg2 * 128 + wv * 32 + l31) * II + half * 8;
#pragma unroll
    for (int s = 0; s < 8; ++s)
      xf[s] = cvt8(*(const float4*)(xrow + s * 16),
                   *(const float4*)(xrow + s * 16 + 4));

#pragma unroll
    for (int tile = 0; tile < 2; ++tile) {
      int mr = m0 + tile * 28 + l31; if (mr > 895) mr = 895;
      const float* mrow = mask + (size_t)mr * II + half * 8;
      short8 af[8];
#pragma unroll
      for (int s = 0; s < 8; ++s)
        af[s] = cvt8(*(const float4*)(mrow + s * 16),
                     *(const float4*)(mrow + s * 16 + 4));
      floatx16 acc;
#pragma unroll
      for (int i = 0; i < 16; ++i) acc[i] = 0.f;
#pragma unroll
      for (int s = 0; s < 8; ++s)
        acc = __builtin_amdgcn_mfma_f32_32x32x16_bf16(af[s], xf[s], acc, 0, 0, 0);

#pragma unroll
      for (int r = 0; r < 16; ++r) {
        int row = (r & 3) + 8 * (r >> 2) + 4 * half;   // 0..31 (m-local)
        if (row < 28) {
          int mrr = m0 + tile * 28 + row;
          float th = thr[mrr > 895 ? 895 : mrr];
          int tl = row / 7;
          int d = row - tl * 7;
          float z = acc[r] - th;
          float o = 0.5f * (z / (1.f + fabsf(z)) + 1.f);
          zsl[((tl + tile * 4) * 128 + wv * 32 + l31) * 8 + d] = __float2half(o);
        }
      }
    }
  }
  __syncthreads();

  // ==================== Phase 2: main contraction ===========================
  {
    const uint4* zsl4 = (const uint4*)smem_raw;
    const int bl = wv * 32 + l31;          // local row 0..127

    __half av[8];
    *(uint4*)av = attnV4[bl];

    floatx16 acc;
#pragma unroll
    for (int i = 0; i < 16; ++i) acc[i] = 0.f;

#pragma unroll
    for (int it = 0; it < 8; ++it) {
      uint4 sv = zsl4[it * 128 + bl];
      uint4 bf[8];
#pragma unroll
      for (int s = 0; s < 8; ++s)
        bf[s] = (l31 < CC) ? lpB4[(it * 8 + s) * 20 + l31 * 2 + half]
                           : make_uint4(0u, 0u, 0u, 0u);

      const __half* sh = (const __half*)&sv;
      float s0 = __half2float(sh[0]), s1 = __half2float(sh[1]);
      float s2 = __half2float(sh[2]), s3 = __half2float(sh[3]);
      float s4 = __half2float(sh[4]), s5 = __half2float(sh[5]);
      float s6 = __half2float(sh[6]);
      float A  = __half2float(av[it]);

      float s0c = 1.f - s0, s1c = 1.f - s1, s2c = 1.f - s2;
      float t0 = s0 * s1, t1 = s0c * s1, t2 = s0 * s1c, t3 = s0c * s1c;
      float pl[8];
      pl[0] = t0 * s2;  pl[1] = t1 * s2;  pl[2] = t2 * s2;  pl[3] = t3 * s2;
      pl[4] = t0 * s2c; pl[5] = t1 * s2c; pl[6] = t2 * s2c; pl[7] = t3 * s2c;
      float sel3 = half ? (1.f - s3) : s3;
      float Af = A * sel3;
      float s4c = 1.f - s4, s5c = 1.f - s5;
      float as6 = Af * s6, as6c = Af * (1.f - s6);
      float u0 = s4 * s5, u1 = s4c * s5, u2 = s4 * s5c, u3 = s4c * s5c;
      float wv8[8];
      wv8[0] = u0 * as6;  wv8[1] = u1 * as6;
      wv8[2] = u2 * as6;  wv8[3] = u3 * as6;
      wv8[4] = u0 * as6c; wv8[5] = u1 * as6c;
      wv8[6] = u2 * as6c; wv8[7] = u3 * as6c;
      __half2 pl2[4];
#pragma unroll
      for (int jp = 0; jp < 4; ++jp)
        pl2[jp] = __float22half2_rn(make_float2(pl[jp * 2], pl[jp * 2 + 1]));

#pragma unroll
      for (int s = 0; s < 8; ++s) {
        union { short8 v; __half2 h[4]; } a0;
        __half2 w2 = __half2half2(__float2half(wv8[s]));
#pragma unroll
        for (int jp = 0; jp < 4; ++jp) a0.h[jp] = __hmul2(pl2[jp], w2);
        acc = __builtin_amdgcn_mfma_f32_32x32x16_f16(
            a0.v, *(const short8*)&bf[s], acc, 0, 0, 0);
      }
    }

    // -------- epilogue: LDS transpose -> coalesced atomicAdd ---------------
    __syncthreads();   // all lpB reads done before red overwrites that region
    float* red = (float*)(smem_raw + 18432);   // [128][10] f32 = 5120 B
    if (l31 < CC) {
#pragma unroll
      for (int r = 0; r < 16; ++r) {
        int row = (r & 3) + 8 * (r >> 2) + 4 * half;
        red[(wv * 32 + row) * 10 + l31] = acc[r];
      }
    }
    __syncthreads();
#pragma unroll
    for (int j = 0; j < 5; ++j) {
      int idx = tid + 256 * j;   // 0..1279
      atomicAdd(out + (size_t)bg2 * 1280 + idx, red[idx]);
    }
  }
}

// ---------------------------------------------------------------------------
extern "C" void kernel_launch(void* const* d_in, const int* in_sizes, int n_in,
                              void* d_out, int out_size, void* d_ws, size_t ws_size,
                              hipStream_t stream) {
  const float* x    = (const float*)d_in[0];
  const float* mask = (const float*)d_in[1];
  const float* thr  = (const float*)d_in[2];
  const float* lo   = (const float*)d_in[3];
  const float* W1   = (const float*)d_in[4];
  const float* b1   = (const float*)d_in[5];
  const float* W2   = (const float*)d_in[6];
  const float* b2   = (const float*)d_in[7];
  float* out = (float*)d_out;
  float* ws  = (float*)d_ws;

  __half*       attnB = (__half*)ws;
  unsigned int* LPb   = (unsigned int*)(ws + OFF_LPB);

  hipMemsetAsync(out, 0, (size_t)out_size * sizeof(float), stream);
  prep_kernel<<<128, 256, 0, stream>>>(x, lo, W1, b1, W2, b2, attnB, LPb);
  main_kernel<<<1024, 256, 0, stream>>>(x, mask, thr, attnB, LPb, out);
}

// Round 4
// 104.667 us; speedup vs baseline: 1.1509x; 1.1221x over previous
//
#include <hip/hip_runtime.h>
#include <hip/hip_bf16.h>
#include <hip/hip_fp16.h>

// Problem: B=8192, T=128, D=7, I=128, C=10, H=64, L=128
// R18 (from R17 counters: main 41.6us, VALU 28.6%, occ 33% -> latency-bound):
//  - main LDS 38.9K -> 16.4K (lpB + attnV read per-lane from global/L2;
//    zsl stays).  launch_bounds(256,6): all 1024 blocks co-resident.
//  - x and mask pre-converted to bf16 in prep (kills 16x/64x redundant pkbf
//    in main + halves its load bytes).  Same rounding as before (cvt8).
//  - XCD swizzle: bg2=(phys&7)+((phys>>7)<<3), tg=(phys>>3)&15 -> the 16
//    blocks sharing x-rows land on one XCD; per-XCD x footprint 256 KB.
//  - zsl is per-wave-private -> NO barrier between phase1 and phase2;
//    barriers only around the epilogue red overlay.
//  - out zeroed by prep blocks (memset launch removed).
// ws layout (float slots):
//   attnB fp16 [8192][128] off 0        (524288)
//   LPb   uint4 compact    off 524288   (81920)   [t][s][n<10][hf]
//   xbf   bf16 [8192][128] off 606208   (524288)
//   mbf   bf16 [896][128]  off 1130496  (57344)

#define BB 8192
#define TT 128
#define II 128
#define CC 10
#define HH 64

#define OFF_LPB 524288
#define OFF_XBF 606208
#define OFF_MBF 1130496

typedef __attribute__((ext_vector_type(8))) short short8;
typedef __attribute__((ext_vector_type(16))) float floatx16;

static __device__ inline unsigned int pkbf(float lo, float hi) {
  __hip_bfloat162 h = __float22bfloat162_rn(make_float2(lo, hi));
  unsigned int u;
  __builtin_memcpy(&u, &h, 4);
  return u;
}

static __device__ inline unsigned int pkh(float lo, float hi) {
  __half2 h = __float22half2_rn(make_float2(lo, hi));
  unsigned int u;
  __builtin_memcpy(&u, &h, 4);
  return u;
}

static __device__ inline short8 cvt8(float4 a, float4 b) {
  union { short8 v; unsigned int u[4]; } r;
  r.u[0] = pkbf(a.x, a.y);
  r.u[1] = pkbf(a.z, a.w);
  r.u[2] = pkbf(b.x, b.y);
  r.u[3] = pkbf(b.z, b.w);
  return r.v;
}

// -------- Kernel A: attn (0..63) | leaf (64..127) | xcvt (128..191) |
//          maskcvt (192..198) | out-zero (199..278) -------------------------
__global__ __launch_bounds__(256, 2) void prep_kernel(
    const float* __restrict__ x, const float* __restrict__ mask,
    const float* __restrict__ lo,
    const float* __restrict__ W1, const float* __restrict__ b1,
    const float* __restrict__ W2, const float* __restrict__ b2,
    __half* __restrict__ attnB, unsigned int* __restrict__ lpbG,
    unsigned short* __restrict__ xbf, unsigned short* __restrict__ mbf,
    float* __restrict__ out) {
  __shared__ __align__(16) char smem_raw[18432];
  const int blk = blockIdx.x;
  const int tid = threadIdx.x;
  const int wv = tid >> 6, lane = tid & 63;
  const int half = lane >> 5, l31 = lane & 31;

  if (blk < 64) {
    // ---------------- attn: 128 b-rows/block, 32/wave (verified) ------------
    const int b0 = blk * 128 + wv * 32;

    short8 axf[8];
    const float* xrow = x + (size_t)(b0 + l31) * II + half * 8;
#pragma unroll
    for (int s = 0; s < 8; ++s)
      axf[s] = cvt8(*(const float4*)(xrow + s * 16),
                    *(const float4*)(xrow + s * 16 + 4));

    floatx16 acch[2];
#pragma unroll
    for (int i = 0; i < 16; ++i) { acch[0][i] = 0.f; acch[1][i] = 0.f; }
#pragma unroll
    for (int s = 0; s < 8; ++s) {
#pragma unroll
      for (int tile = 0; tile < 2; ++tile) {
        union { short8 v; unsigned int u[4]; } wf;
#pragma unroll
        for (int jp = 0; jp < 4; ++jp) {
          int k0 = s * 16 + half * 8 + jp * 2;
          float f0 = W1[(size_t)k0 * HH + tile * 32 + l31];
          float f1 = W1[(size_t)(k0 + 1) * HH + tile * 32 + l31];
          wf.u[jp] = pkbf(f0, f1);
        }
        acch[tile] = __builtin_amdgcn_mfma_f32_32x32x16_bf16(
            axf[s], wf.v, acch[tile], 0, 0, 0);
      }
    }
    __hip_bfloat16* hids = (__hip_bfloat16*)smem_raw + wv * (32 * 72);
#pragma unroll
    for (int tile = 0; tile < 2; ++tile) {
      float bh = b1[tile * 32 + l31];
#pragma unroll
      for (int r = 0; r < 16; ++r) {
        int row = (r & 3) + 8 * (r >> 2) + 4 * half;
        hids[row * 72 + tile * 32 + l31] =
            __float2bfloat16(fmaxf(acch[tile][r] + bh, 0.f));
      }
    }
    __syncthreads();

    short8 ahf[4];
#pragma unroll
    for (int s = 0; s < 4; ++s)
      ahf[s] = *(const short8*)(hids + l31 * 72 + s * 16 + half * 8);

    floatx16 accl[4];
#pragma unroll
    for (int tile = 0; tile < 4; ++tile) {
#pragma unroll
      for (int i = 0; i < 16; ++i) accl[tile][i] = 0.f;
#pragma unroll
      for (int s = 0; s < 4; ++s) {
        union { short8 v; unsigned int u[4]; } wf;
#pragma unroll
        for (int jp = 0; jp < 4; ++jp) {
          int k0 = s * 16 + half * 8 + jp * 2;
          float f0 = W2[(size_t)k0 * TT + tile * 32 + l31];
          float f1 = W2[(size_t)(k0 + 1) * TT + tile * 32 + l31];
          wf.u[jp] = pkbf(f0, f1);
        }
        accl[tile] = __builtin_amdgcn_mfma_f32_32x32x16_bf16(
            ahf[s], wf.v, accl[tile], 0, 0, 0);
      }
      float bt = b2[tile * 32 + l31];
#pragma unroll
      for (int i = 0; i < 16; ++i) accl[tile][i] += bt;
    }

    float mrow[16];
#pragma unroll
    for (int r = 0; r < 16; ++r)
      mrow[r] = fmaxf(fmaxf(accl[0][r], accl[1][r]),
                      fmaxf(accl[2][r], accl[3][r]));
#pragma unroll
    for (int msk = 1; msk <= 16; msk <<= 1)
#pragma unroll
      for (int r = 0; r < 16; ++r)
        mrow[r] = fmaxf(mrow[r], __shfl_xor(mrow[r], msk, 64));
    float srow[16];
#pragma unroll
    for (int r = 0; r < 16; ++r) srow[r] = 0.f;
#pragma unroll
    for (int tile = 0; tile < 4; ++tile)
#pragma unroll
      for (int r = 0; r < 16; ++r) {
        float e = __expf(accl[tile][r] - mrow[r]);
        accl[tile][r] = e;
        srow[r] += e;
      }
#pragma unroll
    for (int msk = 1; msk <= 16; msk <<= 1)
#pragma unroll
      for (int r = 0; r < 16; ++r)
        srow[r] += __shfl_xor(srow[r], msk, 64);
#pragma unroll
    for (int r = 0; r < 16; ++r) srow[r] = 1.f / srow[r];

#pragma unroll
    for (int tile = 0; tile < 4; ++tile)
#pragma unroll
      for (int r = 0; r < 16; ++r) {
        int row = (r & 3) + 8 * (r >> 2) + 4 * half;
        attnB[(size_t)(b0 + row) * TT + tile * 32 + l31] =
            __float2half(accl[tile][r] * srow[r]);
      }

  } else if (blk < 128) {
    // ------- leaf softmax -> COMPACT fp16 B-frags (global, 320 KB) ----------
    float* lps = (float*)smem_raw;   // [2][128][12] f32 = 12288 B
    const int t0 = (blk - 64) * 2;
    {
      int tl = tid >> 7, l = tid & 127;
      const float* row = lo + ((size_t)(t0 + tl) * 128 + l) * CC;
      float v[CC];
      float m = -1e30f;
#pragma unroll
      for (int c = 0; c < CC; ++c) { v[c] = row[c]; m = fmaxf(m, v[c]); }
      float s = 0.f;
#pragma unroll
      for (int c = 0; c < CC; ++c) { v[c] = __expf(v[c] - m); s += v[c]; }
      float inv = 1.f / s;
      float* o = lps + (tl * 128 + l) * 12;
#pragma unroll
      for (int c = 0; c < CC; ++c) o[c] = v[c] * inv;
    }
    __syncthreads();

    // layout: idx = tree*160 + s*20 + n*2 + hf  (uint4)
#pragma unroll
    for (int jj = 0; jj < 2; ++jj) {
      int idx = jj * 256 + tid;          // 0..319
      if (idx < 320) {
        int tl = idx / 160, rem = idx - tl * 160;
        int s = rem / 20, e = rem - s * 20;
        int n = e >> 1, hf = e & 1;
        unsigned int wd[4];
#pragma unroll
        for (int jp = 0; jp < 4; ++jp) {
          int l0 = s * 16 + hf * 8 + jp * 2;
          float f0 = lps[(tl * 128 + l0) * 12 + n];
          float f1 = lps[(tl * 128 + l0 + 1) * 12 + n];
          wd[jp] = pkh(f0, f1);
        }
        ((uint4*)lpbG)[(size_t)(t0 + tl) * 160 + s * 20 + n * 2 + hf] =
            make_uint4(wd[0], wd[1], wd[2], wd[3]);
      }
    }
  } else if (blk < 199) {
    // ------------- f32 -> bf16 conversion of x (64 blks) / mask (7) ---------
    const float* src;
    unsigned short* dst;
    size_t base;
    if (blk < 192) { src = x;    dst = xbf; base = (size_t)(blk - 128) * 16384; }
    else           { src = mask; dst = mbf; base = (size_t)(blk - 192) * 16384; }
#pragma unroll
    for (int j = 0; j < 8; ++j) {
      size_t e = base + (size_t)j * 2048 + (size_t)tid * 8;
      float4 a = *(const float4*)(src + e);
      float4 b = *(const float4*)(src + e + 4);
      *(short8*)(dst + e) = cvt8(a, b);
    }
  } else {
    // ------------- zero out (re-zeroed EVERY launch; atomics follow) --------
    ((float4*)out)[(blk - 199) * 256 + tid] = make_float4(0.f, 0.f, 0.f, 0.f);
  }
}

// -------- Kernel B: zs (LDS, per-wave) + main contraction -------------------
// 1024 blocks, XCD-swizzled (bg2,tg). LDS 16384 B only -> 6 blocks/CU
// resident (launch_bounds(256,6)); all blocks co-resident at t=0.
__global__ __launch_bounds__(256, 6) void main_kernel(
    const unsigned short* __restrict__ xbf, const unsigned short* __restrict__ mbf,
    const float* __restrict__ thr, const __half* __restrict__ attnB,
    const unsigned int* __restrict__ lpbG, float* __restrict__ out) {
  __shared__ __align__(16) char smem_raw[16384];
  const int tid = threadIdx.x;
  const int wv = tid >> 6, lane = tid & 63;
  const int half = lane >> 5, l31 = lane & 31;
  const int phys = blockIdx.x;
  const int bg2 = (phys & 7) + ((phys >> 7) << 3);  // same-bg2 -> same XCD
  const int tg  = (phys >> 3) & 15;
  const int bl = wv * 32 + l31;      // own local row 0..127

  __half* zsl = (__half*)smem_raw;   // [8 tree][128 row][8]

  // early loads: attn vector (own row) — hides under phase 1
  __half av[8];
  *(uint4*)av = ((const uint4*)attnB)[(size_t)(bg2 * 128 + bl) * 16 + tg];

  // ==================== Phase 1: zs -> LDS (per-wave rows) ==================
  {
    const int m0 = tg * 56;
    short8 xf[8];
    const unsigned short* xr = xbf + (size_t)(bg2 * 128 + bl) * II + half * 8;
#pragma unroll
    for (int s = 0; s < 8; ++s) xf[s] = *(const short8*)(xr + s * 16);

#pragma unroll
    for (int tile = 0; tile < 2; ++tile) {
      int mr = m0 + tile * 28 + l31; if (mr > 895) mr = 895;
      const unsigned short* mrow = mbf + (size_t)mr * II + half * 8;
      short8 af[8];
#pragma unroll
      for (int s = 0; s < 8; ++s) af[s] = *(const short8*)(mrow + s * 16);
      float th[16];
#pragma unroll
      for (int r = 0; r < 16; ++r) {
        int row = (r & 3) + 8 * (r >> 2) + 4 * half;
        int mrr = m0 + tile * 28 + row;
        th[r] = thr[mrr > 895 ? 895 : mrr];
      }
      floatx16 acc;
#pragma unroll
      for (int i = 0; i < 16; ++i) acc[i] = 0.f;
#pragma unroll
      for (int s = 0; s < 8; ++s)
        acc = __builtin_amdgcn_mfma_f32_32x32x16_bf16(af[s], xf[s], acc, 0, 0, 0);

#pragma unroll
      for (int r = 0; r < 16; ++r) {
        int row = (r & 3) + 8 * (r >> 2) + 4 * half;   // m-local 0..31
        if (row < 28) {
          int tl = row / 7;
          int d = row - tl * 7;
          float z = acc[r] - th[r];
          float o = 0.5f * (z / (1.f + fabsf(z)) + 1.f);
          zsl[((tl + tile * 4) * 128 + bl) * 8 + d] = __float2half(o);
        }
      }
    }
  }
  // NO barrier: each wave reads only the zsl rows it wrote (lgkmcnt suffices)

  // ==================== Phase 2: main contraction ===========================
  {
    const uint4* zsl4 = (const uint4*)smem_raw;
    const uint4* lpt = (const uint4*)lpbG + (size_t)tg * 1280;

    floatx16 acc;
#pragma unroll
    for (int i = 0; i < 16; ++i) acc[i] = 0.f;

#pragma unroll
    for (int it = 0; it < 8; ++it) {
      uint4 bf[8];
#pragma unroll
      for (int s = 0; s < 8; ++s)
        bf[s] = (l31 < CC) ? lpt[(it * 8 + s) * 20 + l31 * 2 + half]
                           : make_uint4(0u, 0u, 0u, 0u);
      uint4 sv = zsl4[it * 128 + bl];

      const __half* sh = (const __half*)&sv;
      float s0 = __half2float(sh[0]), s1 = __half2float(sh[1]);
      float s2 = __half2float(sh[2]), s3 = __half2float(sh[3]);
      float s4 = __half2float(sh[4]), s5 = __half2float(sh[5]);
      float s6 = __half2float(sh[6]);
      float A  = __half2float(av[it]);

      float s0c = 1.f - s0, s1c = 1.f - s1, s2c = 1.f - s2;
      float t0 = s0 * s1, t1 = s0c * s1, t2 = s0 * s1c, t3 = s0c * s1c;
      float pl[8];
      pl[0] = t0 * s2;  pl[1] = t1 * s2;  pl[2] = t2 * s2;  pl[3] = t3 * s2;
      pl[4] = t0 * s2c; pl[5] = t1 * s2c; pl[6] = t2 * s2c; pl[7] = t3 * s2c;
      float sel3 = half ? (1.f - s3) : s3;
      float Af = A * sel3;
      float s4c = 1.f - s4, s5c = 1.f - s5;
      float as6 = Af * s6, as6c = Af * (1.f - s6);
      float u0 = s4 * s5, u1 = s4c * s5, u2 = s4 * s5c, u3 = s4c * s5c;
      float wv8[8];
      wv8[0] = u0 * as6;  wv8[1] = u1 * as6;
      wv8[2] = u2 * as6;  wv8[3] = u3 * as6;
      wv8[4] = u0 * as6c; wv8[5] = u1 * as6c;
      wv8[6] = u2 * as6c; wv8[7] = u3 * as6c;
      __half2 pl2[4];
#pragma unroll
      for (int jp = 0; jp < 4; ++jp)
        pl2[jp] = __float22half2_rn(make_float2(pl[jp * 2], pl[jp * 2 + 1]));

#pragma unroll
      for (int s = 0; s < 8; ++s) {
        union { short8 v; __half2 h[4]; } a0;
        __half2 w2 = __half2half2(__float2half(wv8[s]));
#pragma unroll
        for (int jp = 0; jp < 4; ++jp) a0.h[jp] = __hmul2(pl2[jp], w2);
        acc = __builtin_amdgcn_mfma_f32_32x32x16_f16(
            a0.v, *(const short8*)&bf[s], acc, 0, 0, 0);
      }
    }

    // -------- epilogue: red overlays zsl (barrier both sides) --------------
    __syncthreads();   // every wave done reading its zsl before overlay write
    float* red = (float*)smem_raw;   // [128][10] f32 = 5120 B
    if (l31 < CC) {
#pragma unroll
      for (int r = 0; r < 16; ++r) {
        int row = (r & 3) + 8 * (r >> 2) + 4 * half;
        red[(wv * 32 + row) * 10 + l31] = acc[r];
      }
    }
    __syncthreads();
#pragma unroll
    for (int j = 0; j < 5; ++j) {
      int idx = tid + 256 * j;   // 0..1279
      atomicAdd(out + (size_t)bg2 * 1280 + idx, red[idx]);
    }
  }
}

// ---------------------------------------------------------------------------
extern "C" void kernel_launch(void* const* d_in, const int* in_sizes, int n_in,
                              void* d_out, int out_size, void* d_ws, size_t ws_size,
                              hipStream_t stream) {
  const float* x    = (const float*)d_in[0];
  const float* mask = (const float*)d_in[1];
  const float* thr  = (const float*)d_in[2];
  const float* lo   = (const float*)d_in[3];
  const float* W1   = (const float*)d_in[4];
  const float* b1   = (const float*)d_in[5];
  const float* W2   = (const float*)d_in[6];
  const float* b2   = (const float*)d_in[7];
  float* out = (float*)d_out;
  float* ws  = (float*)d_ws;

  __half*        attnB = (__half*)ws;
  unsigned int*  LPb   = (unsigned int*)(ws + OFF_LPB);
  unsigned short* xbf  = (unsigned short*)(ws + OFF_XBF);
  unsigned short* mbf  = (unsigned short*)(ws + OFF_MBF);

  prep_kernel<<<279, 256, 0, stream>>>(x, mask, lo, W1, b1, W2, b2,
                                       attnB, LPb, xbf, mbf, out);
  main_kernel<<<1024, 256, 0, stream>>>(xbf, mbf, thr, attnB, LPb, out);
}

// Round 5
// 101.692 us; speedup vs baseline: 1.1845x; 1.0293x over previous
//
#include <hip/hip_runtime.h>
#include <hip/hip_bf16.h>
#include <hip/hip_fp16.h>

// Problem: B=8192, T=128, D=7, I=128, C=10, H=64, L=128
// R19 (R18: 104.7us total = fill 40 + prep ~18 + main ~27 + gaps):
//  - prep: uniform 64-thread blocks (708), attn as 256 ONE-WAVE blocks of
//    32 rows (wave-private hids, no cross-wave barrier) -> whole machine
//    covered, ~4x less prep latency.
//  - main: lpt (leaf-prob B-frags) double-buffer prefetch across the it-loop
//    (fully unrolled, static indices) hides ~250cy L2 latency per tree under
//    the previous tree's VALU+MFMA. launch_bounds(256,4): grid 1024 is
//    4 blocks/CU anyway; gives allocator 128 VGPR for the +64 prefetch regs.
// ws layout (float slots):
//   attnB fp16 [8192][128] off 0        (524288)
//   LPb   uint4 compact    off 524288   (81920)   [t][s][n<10][hf]
//   xbf   bf16 [8192][128] off 606208   (524288)
//   mbf   bf16 [896][128]  off 1130496  (57344)

#define BB 8192
#define TT 128
#define II 128
#define CC 10
#define HH 64

#define OFF_LPB 524288
#define OFF_XBF 606208
#define OFF_MBF 1130496

typedef __attribute__((ext_vector_type(8))) short short8;
typedef __attribute__((ext_vector_type(16))) float floatx16;

static __device__ inline unsigned int pkbf(float lo, float hi) {
  __hip_bfloat162 h = __float22bfloat162_rn(make_float2(lo, hi));
  unsigned int u;
  __builtin_memcpy(&u, &h, 4);
  return u;
}

static __device__ inline unsigned int pkh(float lo, float hi) {
  __half2 h = __float22half2_rn(make_float2(lo, hi));
  unsigned int u;
  __builtin_memcpy(&u, &h, 4);
  return u;
}

static __device__ inline short8 cvt8(float4 a, float4 b) {
  union { short8 v; unsigned int u[4]; } r;
  r.u[0] = pkbf(a.x, a.y);
  r.u[1] = pkbf(a.z, a.w);
  r.u[2] = pkbf(b.x, b.y);
  r.u[3] = pkbf(b.z, b.w);
  return r.v;
}

// ---- prep: 708 blocks x 64 thr ---------------------------------------------
// [0,256): attn, 32 rows/block (one wave)
// [256,384): leaf softmax, 1 tree/block
// [384,640): x f32->bf16, 4096 elems/block
// [640,668): mask f32->bf16, 4096 elems/block
// [668,708): zero out, 512 float4/block
__global__ __launch_bounds__(64) void prep_kernel(
    const float* __restrict__ x, const float* __restrict__ mask,
    const float* __restrict__ lo,
    const float* __restrict__ W1, const float* __restrict__ b1,
    const float* __restrict__ W2, const float* __restrict__ b2,
    __half* __restrict__ attnB, unsigned int* __restrict__ lpbG,
    unsigned short* __restrict__ xbf, unsigned short* __restrict__ mbf,
    float* __restrict__ out) {
  __shared__ __align__(16) char smem_raw[6144];
  const int blk = blockIdx.x;
  const int lane = threadIdx.x;           // 0..63 (one wave)
  const int half = lane >> 5, l31 = lane & 31;

  if (blk < 256) {
    // ---------------- attn: 32 rows, one wave (R0-verified math) ------------
    const int b0 = blk * 32;

    short8 axf[8];
    const float* xrow = x + (size_t)(b0 + l31) * II + half * 8;
#pragma unroll
    for (int s = 0; s < 8; ++s)
      axf[s] = cvt8(*(const float4*)(xrow + s * 16),
                    *(const float4*)(xrow + s * 16 + 4));

    floatx16 acch[2];
#pragma unroll
    for (int i = 0; i < 16; ++i) { acch[0][i] = 0.f; acch[1][i] = 0.f; }
#pragma unroll
    for (int s = 0; s < 8; ++s) {
#pragma unroll
      for (int tile = 0; tile < 2; ++tile) {
        union { short8 v; unsigned int u[4]; } wf;
#pragma unroll
        for (int jp = 0; jp < 4; ++jp) {
          int k0 = s * 16 + half * 8 + jp * 2;
          float f0 = W1[(size_t)k0 * HH + tile * 32 + l31];
          float f1 = W1[(size_t)(k0 + 1) * HH + tile * 32 + l31];
          wf.u[jp] = pkbf(f0, f1);
        }
        acch[tile] = __builtin_amdgcn_mfma_f32_32x32x16_bf16(
            axf[s], wf.v, acch[tile], 0, 0, 0);
      }
    }
    __hip_bfloat16* hids = (__hip_bfloat16*)smem_raw;   // [32][72]
#pragma unroll
    for (int tile = 0; tile < 2; ++tile) {
      float bh = b1[tile * 32 + l31];
#pragma unroll
      for (int r = 0; r < 16; ++r) {
        int row = (r & 3) + 8 * (r >> 2) + 4 * half;
        hids[row * 72 + tile * 32 + l31] =
            __float2bfloat16(fmaxf(acch[tile][r] + bh, 0.f));
      }
    }
    __syncthreads();   // single wave: cheap; orders LDS write->read

    short8 ahf[4];
#pragma unroll
    for (int s = 0; s < 4; ++s)
      ahf[s] = *(const short8*)(hids + l31 * 72 + s * 16 + half * 8);

    floatx16 accl[4];
#pragma unroll
    for (int tile = 0; tile < 4; ++tile) {
#pragma unroll
      for (int i = 0; i < 16; ++i) accl[tile][i] = 0.f;
#pragma unroll
      for (int s = 0; s < 4; ++s) {
        union { short8 v; unsigned int u[4]; } wf;
#pragma unroll
        for (int jp = 0; jp < 4; ++jp) {
          int k0 = s * 16 + half * 8 + jp * 2;
          float f0 = W2[(size_t)k0 * TT + tile * 32 + l31];
          float f1 = W2[(size_t)(k0 + 1) * TT + tile * 32 + l31];
          wf.u[jp] = pkbf(f0, f1);
        }
        accl[tile] = __builtin_amdgcn_mfma_f32_32x32x16_bf16(
            ahf[s], wf.v, accl[tile], 0, 0, 0);
      }
      float bt = b2[tile * 32 + l31];
#pragma unroll
      for (int i = 0; i < 16; ++i) accl[tile][i] += bt;
    }

    float mrow[16];
#pragma unroll
    for (int r = 0; r < 16; ++r)
      mrow[r] = fmaxf(fmaxf(accl[0][r], accl[1][r]),
                      fmaxf(accl[2][r], accl[3][r]));
#pragma unroll
    for (int msk = 1; msk <= 16; msk <<= 1)
#pragma unroll
      for (int r = 0; r < 16; ++r)
        mrow[r] = fmaxf(mrow[r], __shfl_xor(mrow[r], msk, 64));
    float srow[16];
#pragma unroll
    for (int r = 0; r < 16; ++r) srow[r] = 0.f;
#pragma unroll
    for (int tile = 0; tile < 4; ++tile)
#pragma unroll
      for (int r = 0; r < 16; ++r) {
        float e = __expf(accl[tile][r] - mrow[r]);
        accl[tile][r] = e;
        srow[r] += e;
      }
#pragma unroll
    for (int msk = 1; msk <= 16; msk <<= 1)
#pragma unroll
      for (int r = 0; r < 16; ++r)
        srow[r] += __shfl_xor(srow[r], msk, 64);
#pragma unroll
    for (int r = 0; r < 16; ++r) srow[r] = 1.f / srow[r];

#pragma unroll
    for (int tile = 0; tile < 4; ++tile)
#pragma unroll
      for (int r = 0; r < 16; ++r) {
        int row = (r & 3) + 8 * (r >> 2) + 4 * half;
        attnB[(size_t)(b0 + row) * TT + tile * 32 + l31] =
            __float2half(accl[tile][r] * srow[r]);
      }

  } else if (blk < 384) {
    // ------- leaf softmax (1 tree) -> COMPACT fp16 B-frags ------------------
    float* lps = (float*)smem_raw;   // [128][12] f32 = 6144 B
    const int t0 = blk - 256;
#pragma unroll
    for (int rr = 0; rr < 2; ++rr) {
      int l = lane * 2 + rr;         // 0..127
      const float* row = lo + ((size_t)t0 * 128 + l) * CC;
      float v[CC];
      float m = -1e30f;
#pragma unroll
      for (int c = 0; c < CC; ++c) { v[c] = row[c]; m = fmaxf(m, v[c]); }
      float s = 0.f;
#pragma unroll
      for (int c = 0; c < CC; ++c) { v[c] = __expf(v[c] - m); s += v[c]; }
      float inv = 1.f / s;
      float* o = lps + l * 12;
#pragma unroll
      for (int c = 0; c < CC; ++c) o[c] = v[c] * inv;
    }
    __syncthreads();

    // layout: idx = tree*160 + s*20 + n*2 + hf  (uint4)
#pragma unroll
    for (int jj = 0; jj < 3; ++jj) {
      int idx = jj * 64 + lane;      // 0..191
      if (idx < 160) {
        int s = idx / 20, e = idx - s * 20;
        int n = e >> 1, hf = e & 1;
        unsigned int wd[4];
#pragma unroll
        for (int jp = 0; jp < 4; ++jp) {
          int l0 = s * 16 + hf * 8 + jp * 2;
          float f0 = lps[l0 * 12 + n];
          float f1 = lps[(l0 + 1) * 12 + n];
          wd[jp] = pkh(f0, f1);
        }
        ((uint4*)lpbG)[(size_t)t0 * 160 + idx] =
            make_uint4(wd[0], wd[1], wd[2], wd[3]);
      }
    }
  } else if (blk < 668) {
    // ------------- f32 -> bf16: x (256 blocks) / mask (28 blocks) -----------
    const float* src;
    unsigned short* dst;
    size_t base;
    if (blk < 640) { src = x;    dst = xbf; base = (size_t)(blk - 384) * 4096; }
    else           { src = mask; dst = mbf; base = (size_t)(blk - 640) * 4096; }
#pragma unroll
    for (int j = 0; j < 8; ++j) {
      size_t e = base + (size_t)j * 512 + (size_t)lane * 8;
      float4 a = *(const float4*)(src + e);
      float4 b = *(const float4*)(src + e + 4);
      *(short8*)(dst + e) = cvt8(a, b);
    }
  } else {
    // ------------- zero out (re-zeroed EVERY launch; atomics follow) --------
    const int base4 = (blk - 668) * 512;
#pragma unroll
    for (int j = 0; j < 8; ++j)
      ((float4*)out)[base4 + j * 64 + lane] = make_float4(0.f, 0.f, 0.f, 0.f);
  }
}

// -------- main: zs (LDS, per-wave) + contraction, lpt double-buffered -------
// 1024 blocks, XCD-swizzled. LDS 16 KB; grid-limited 4 blocks/CU.
__global__ __launch_bounds__(256, 4) void main_kernel(
    const unsigned short* __restrict__ xbf, const unsigned short* __restrict__ mbf,
    const float* __restrict__ thr, const __half* __restrict__ attnB,
    const unsigned int* __restrict__ lpbG, float* __restrict__ out) {
  __shared__ __align__(16) char smem_raw[16384];
  const int tid = threadIdx.x;
  const int wv = tid >> 6, lane = tid & 63;
  const int half = lane >> 5, l31 = lane & 31;
  const int phys = blockIdx.x;
  const int bg2 = (phys & 7) + ((phys >> 7) << 3);  // same-bg2 -> same XCD
  const int tg  = (phys >> 3) & 15;
  const int bl = wv * 32 + l31;      // own local row 0..127

  __half* zsl = (__half*)smem_raw;   // [8 tree][128 row][8]

  // early load: attn vector for own row (hides under phase 1)
  __half av[8];
  *(uint4*)av = ((const uint4*)attnB)[(size_t)(bg2 * 128 + bl) * 16 + tg];

  // ==================== Phase 1: zs -> LDS (per-wave rows) ==================
  {
    const int m0 = tg * 56;
    short8 xf[8];
    const unsigned short* xr = xbf + (size_t)(bg2 * 128 + bl) * II + half * 8;
#pragma unroll
    for (int s = 0; s < 8; ++s) xf[s] = *(const short8*)(xr + s * 16);

#pragma unroll
    for (int tile = 0; tile < 2; ++tile) {
      int mr = m0 + tile * 28 + l31; if (mr > 895) mr = 895;
      const unsigned short* mrow = mbf + (size_t)mr * II + half * 8;
      short8 af[8];
#pragma unroll
      for (int s = 0; s < 8; ++s) af[s] = *(const short8*)(mrow + s * 16);
      float th[16];
#pragma unroll
      for (int r = 0; r < 16; ++r) {
        int row = (r & 3) + 8 * (r >> 2) + 4 * half;
        int mrr = m0 + tile * 28 + row;
        th[r] = thr[mrr > 895 ? 895 : mrr];
      }
      floatx16 acc;
#pragma unroll
      for (int i = 0; i < 16; ++i) acc[i] = 0.f;
#pragma unroll
      for (int s = 0; s < 8; ++s)
        acc = __builtin_amdgcn_mfma_f32_32x32x16_bf16(af[s], xf[s], acc, 0, 0, 0);

#pragma unroll
      for (int r = 0; r < 16; ++r) {
        int row = (r & 3) + 8 * (r >> 2) + 4 * half;   // m-local 0..31
        if (row < 28) {
          int tl = row / 7;
          int d = row - tl * 7;
          float z = acc[r] - th[r];
          float o = 0.5f * (z / (1.f + fabsf(z)) + 1.f);
          zsl[((tl + tile * 4) * 128 + bl) * 8 + d] = __float2half(o);
        }
      }
    }
  }
  // NO barrier: each wave reads only the zsl rows it wrote

  // ==================== Phase 2: contraction, double-buffered lpt ===========
  {
    const uint4* zsl4 = (const uint4*)smem_raw;
    const uint4* lpt = (const uint4*)lpbG + (size_t)tg * 1280;

    floatx16 acc;
#pragma unroll
    for (int i = 0; i < 16; ++i) acc[i] = 0.f;

    auto dostep = [&](int it, const uint4* bf) {
      uint4 sv = zsl4[it * 128 + bl];
      const __half* sh = (const __half*)&sv;
      float s0 = __half2float(sh[0]), s1 = __half2float(sh[1]);
      float s2 = __half2float(sh[2]), s3 = __half2float(sh[3]);
      float s4 = __half2float(sh[4]), s5 = __half2float(sh[5]);
      float s6 = __half2float(sh[6]);
      float A  = __half2float(av[it]);

      float s0c = 1.f - s0, s1c = 1.f - s1, s2c = 1.f - s2;
      float t0 = s0 * s1, t1 = s0c * s1, t2 = s0 * s1c, t3 = s0c * s1c;
      float pl[8];
      pl[0] = t0 * s2;  pl[1] = t1 * s2;  pl[2] = t2 * s2;  pl[3] = t3 * s2;
      pl[4] = t0 * s2c; pl[5] = t1 * s2c; pl[6] = t2 * s2c; pl[7] = t3 * s2c;
      float sel3 = half ? (1.f - s3) : s3;
      float Af = A * sel3;
      float s4c = 1.f - s4, s5c = 1.f - s5;
      float as6 = Af * s6, as6c = Af * (1.f - s6);
      float u0 = s4 * s5, u1 = s4c * s5, u2 = s4 * s5c, u3 = s4c * s5c;
      float wv8[8];
      wv8[0] = u0 * as6;  wv8[1] = u1 * as6;
      wv8[2] = u2 * as6;  wv8[3] = u3 * as6;
      wv8[4] = u0 * as6c; wv8[5] = u1 * as6c;
      wv8[6] = u2 * as6c; wv8[7] = u3 * as6c;
      __half2 pl2[4];
#pragma unroll
      for (int jp = 0; jp < 4; ++jp)
        pl2[jp] = __float22half2_rn(make_float2(pl[jp * 2], pl[jp * 2 + 1]));

#pragma unroll
      for (int s = 0; s < 8; ++s) {
        union { short8 v; __half2 h[4]; } a0;
        __half2 w2 = __half2half2(__float2half(wv8[s]));
#pragma unroll
        for (int jp = 0; jp < 4; ++jp) a0.h[jp] = __hmul2(pl2[jp], w2);
        acc = __builtin_amdgcn_mfma_f32_32x32x16_f16(
            a0.v, *(const short8*)&bf[s], acc, 0, 0, 0);
      }
    };

#define PF(dst, itn)                                                       \
  _Pragma("unroll") for (int s = 0; s < 8; ++s)                            \
      dst[s] = (l31 < CC) ? lpt[((itn) * 8 + s) * 20 + l31 * 2 + half]     \
                          : make_uint4(0u, 0u, 0u, 0u);

    uint4 bf0[8], bf1[8];
    PF(bf0, 0)
#pragma unroll
    for (int ith = 0; ith < 4; ++ith) {
      const int it = ith * 2;
      PF(bf1, it + 1)            // issue next-tree loads...
      dostep(it, bf0);           // ...hidden under this tree's VALU+MFMA
      if (ith < 3) { PF(bf0, it + 2) }
      dostep(it + 1, bf1);
    }
#undef PF

    // -------- epilogue: red overlays zsl (barrier both sides) --------------
    __syncthreads();   // every wave done reading its zsl before overlay write
    float* red = (float*)smem_raw;   // [128][10] f32 = 5120 B
    if (l31 < CC) {
#pragma unroll
      for (int r = 0; r < 16; ++r) {
        int row = (r & 3) + 8 * (r >> 2) + 4 * half;
        red[(wv * 32 + row) * 10 + l31] = acc[r];
      }
    }
    __syncthreads();
#pragma unroll
    for (int j = 0; j < 5; ++j) {
      int idx = tid + 256 * j;   // 0..1279
      atomicAdd(out + (size_t)bg2 * 1280 + idx, red[idx]);
    }
  }
}

// ---------------------------------------------------------------------------
extern "C" void kernel_launch(void* const* d_in, const int* in_sizes, int n_in,
                              void* d_out, int out_size, void* d_ws, size_t ws_size,
                              hipStream_t stream) {
  const float* x    = (const float*)d_in[0];
  const float* mask = (const float*)d_in[1];
  const float* thr  = (const float*)d_in[2];
  const float* lo   = (const float*)d_in[3];
  const float* W1   = (const float*)d_in[4];
  const float* b1   = (const float*)d_in[5];
  const float* W2   = (const float*)d_in[6];
  const float* b2   = (const float*)d_in[7];
  float* out = (float*)d_out;
  float* ws  = (float*)d_ws;

  __half*         attnB = (__half*)ws;
  unsigned int*   LPb   = (unsigned int*)(ws + OFF_LPB);
  unsigned short* xbf   = (unsigned short*)(ws + OFF_XBF);
  unsigned short* mbf   = (unsigned short*)(ws + OFF_MBF);

  prep_kernel<<<708, 64, 0, stream>>>(x, mask, lo, W1, b1, W2, b2,
                                      attnB, LPb, xbf, mbf, out);
  main_kernel<<<1024, 256, 0, stream>>>(xbf, mbf, thr, attnB, LPb, out);
}